// Round 8
// baseline (492.322 us; speedup 1.0000x reference)
//
#include <hip/hip_runtime.h>

#define NN 100000
#define NE 1600000
#define NG 1024
#define D 64
#define DE 6
#define FAN 70
#define EPS 1e-5f

#define ENC_NEGINF 0x007FFFFFu
#define NINF (-__builtin_inff())

#define NBUK 196      // dst buckets of 512 nodes
#define TILE 1600     // edges per binA block
#define NBLKA 1000    // NE / TILE
#define ACAP 24       // per-(bucket,block) deterministic slot capacity (lambda=8.16)
#define SCAP 1024     // per-bucket spill capacity (rare path)
#define BCAP 10240    // binB LDS esrc capacity

__device__ __forceinline__ unsigned enc(float f) {
    unsigned u = __float_as_uint(f);
    return (u & 0x80000000u) ? ~u : (u | 0x80000000u);
}
__device__ __forceinline__ float dec(unsigned u) {
    return (u & 0x80000000u) ? __uint_as_float(u & 0x7FFFFFFFu) : __uint_as_float(~u);
}
__device__ __forceinline__ unsigned bfr(float f) {   // fp32 -> bf16 bits, RNE
    unsigned u = __float_as_uint(f);
    return (u + 0x7FFFu + ((u >> 16) & 1)) >> 16;
}
__device__ __forceinline__ float blo(unsigned w) { return __uint_as_float(w << 16); }
__device__ __forceinline__ float bhi(unsigned w) { return __uint_as_float(w & 0xFFFF0000u); }

__global__ void k_fill_u32x4(uint4* __restrict__ p, unsigned v, int n4) {
    int i = blockIdx.x * 256 + threadIdx.x;
    if (i < n4) p[i] = make_uint4(v, v, v, v);
}

// fp32 [NN][64] -> bf16-packed [NN][32] u32
__global__ void k_cast(const float4* __restrict__ in, uint2* __restrict__ out, int n4) {
    int i = blockIdx.x * 256 + threadIdx.x;
    if (i < n4) {
        float4 v = in[i];
        out[i] = make_uint2(bfr(v.x) | (bfr(v.y) << 16), bfr(v.z) | (bfr(v.w) << 16));
    }
}

// pass A: deterministic slots gbuck[b][blk][ACAP], entries (eid<<9 | dst&511)
__launch_bounds__(256)
__global__ void k_binA(const int* __restrict__ dst,
                       unsigned* __restrict__ gbuck, int* __restrict__ cntA,
                       int* __restrict__ scnt, unsigned* __restrict__ sbuf) {
    __shared__ int cnt[NBUK];
    int tid = threadIdx.x, blk = blockIdx.x;
    for (int i = tid; i < NBUK; i += 256) cnt[i] = 0;
    __syncthreads();
    int e0 = blk * TILE;
    int e1 = min(e0 + TILE, NE);
    for (int e = e0 + tid; e < e1; e += 256) {
        int d = dst[e];
        int b = d >> 9;
        unsigned ent = ((unsigned)e << 9) | (unsigned)(d & 511);
        int pos = atomicAdd(&cnt[b], 1);
        if (pos < ACAP) gbuck[((size_t)b * NBLKA + blk) * ACAP + pos] = ent;
        else {  // rare spill
            int sp = atomicAdd(&scnt[b], 1);
            if (sp < SCAP) sbuf[b * SCAP + sp] = ent;
        }
    }
    __syncthreads();
    for (int i = tid; i < NBUK; i += 256) cntA[blk * NBUK + i] = min(cnt[i], ACAP);
}

// per-bucket totals
__global__ void k_buksum(const int* __restrict__ cntA, const int* __restrict__ scnt,
                         int* __restrict__ buktot) {
    __shared__ int red[256];
    int b = blockIdx.x, tid = threadIdx.x;
    int sum = 0;
    for (int blk = tid; blk < NBLKA; blk += 256) sum += cntA[blk * NBUK + b];
    red[tid] = sum;
    __syncthreads();
    for (int off = 128; off > 0; off >>= 1) {
        if (tid < off) red[tid] += red[tid + off];
        __syncthreads();
    }
    if (tid == 0) buktot[b] = red[0] + min(scnt[b], SCAP);
}

// exclusive scan of 196 bucket totals
__global__ void k_bukscan(const int* __restrict__ buktot, int* __restrict__ bukbase) {
    __shared__ int s[256];
    int t = threadIdx.x;
    int c = (t < NBUK) ? buktot[t] : 0;
    s[t] = c;
    __syncthreads();
    for (int off = 1; off < 256; off <<= 1) {
        int y = (t >= off) ? s[t - off] : 0;
        __syncthreads();
        s[t] += y;
        __syncthreads();
    }
    if (t < NBUK) bukbase[t] = s[t] - c;
}

// pass B: per bucket — count+scan -> rowptr; scatter esrc via LDS; eagg via LDS atomicMax
__launch_bounds__(512)
__global__ void k_binB(const unsigned* __restrict__ gbuck, const int* __restrict__ cntA,
                       const int* __restrict__ scnt, const unsigned* __restrict__ sbuf,
                       const int* __restrict__ bukbase,
                       const int* __restrict__ src, const float* __restrict__ ea,
                       int* __restrict__ rowptr, int* __restrict__ esrc,
                       unsigned* __restrict__ eaggk) {
    __shared__ int cnt[512];
    __shared__ int base[512];
    __shared__ unsigned el[BCAP];            // 40 KB
    __shared__ unsigned emax[512 * DE];      // 12 KB
    int b = blockIdx.x, tid = threadIdx.x;
    int nb = b << 9;
    int nend = min(nb + 512, NN);
    cnt[tid] = 0;
    for (int i = tid; i < 512 * DE; i += 512) emax[i] = ENC_NEGINF;
    __syncthreads();
    int sc = min(scnt[b], SCAP);
    // pass 1: per-node counts
    for (int blk = tid; blk < NBLKA; blk += 512) {
        int c = cntA[blk * NBUK + b];
        const unsigned* p = &gbuck[((size_t)b * NBLKA + blk) * ACAP];
        for (int i = 0; i < c; ++i) atomicAdd(&cnt[p[i] & 511], 1);
    }
    for (int i = tid; i < sc; i += 512) atomicAdd(&cnt[sbuf[b * SCAP + i] & 511], 1);
    __syncthreads();
    // inclusive scan of 512 counts
    int v = cnt[tid];
    base[tid] = v;
    __syncthreads();
    for (int off = 1; off < 512; off <<= 1) {
        int y = (tid >= off) ? base[tid - off] : 0;
        __syncthreads();
        base[tid] += y;
        __syncthreads();
    }
    int excl = base[tid] - v;
    int rb = bukbase[b];
    if (nb + tid < NN) rowptr[nb + tid] = rb + excl;
    if (b == NBUK - 1 && tid == 0) rowptr[NN] = NE;
    int regsz = base[511];
    __syncthreads();
    cnt[tid] = excl;   // reuse as cursor
    __syncthreads();
    // pass 2: scatter + edge_attr seg-max (LDS)
    if (regsz <= BCAP) {
        for (int blk = tid; blk < NBLKA; blk += 512) {
            int c = cntA[blk * NBUK + b];
            const unsigned* p = &gbuck[((size_t)b * NBLKA + blk) * ACAP];
            for (int i = 0; i < c; ++i) {
                unsigned ent = p[i];
                int loc = ent & 511;
                int eid = ent >> 9;
                int pos = atomicAdd(&cnt[loc], 1);
                el[pos] = (unsigned)src[eid];
                const float* pe = &ea[(size_t)eid * DE];
                #pragma unroll
                for (int t = 0; t < DE; ++t) atomicMax(&emax[loc * DE + t], enc(pe[t]));
            }
        }
        for (int i = tid; i < sc; i += 512) {
            unsigned ent = sbuf[b * SCAP + i];
            int loc = ent & 511;
            int eid = ent >> 9;
            int pos = atomicAdd(&cnt[loc], 1);
            el[pos] = (unsigned)src[eid];
            const float* pe = &ea[(size_t)eid * DE];
            #pragma unroll
            for (int t = 0; t < DE; ++t) atomicMax(&emax[loc * DE + t], enc(pe[t]));
        }
        __syncthreads();
        for (int i = tid; i < regsz; i += 512) esrc[rb + i] = (int)el[i];
    } else {  // capacity fallback: direct global scatter (correct, slower)
        for (int blk = tid; blk < NBLKA; blk += 512) {
            int c = cntA[blk * NBUK + b];
            const unsigned* p = &gbuck[((size_t)b * NBLKA + blk) * ACAP];
            for (int i = 0; i < c; ++i) {
                unsigned ent = p[i];
                int loc = ent & 511;
                int eid = ent >> 9;
                int pos = atomicAdd(&cnt[loc], 1);
                esrc[rb + pos] = src[eid];
                const float* pe = &ea[(size_t)eid * DE];
                #pragma unroll
                for (int t = 0; t < DE; ++t) atomicMax(&emax[loc * DE + t], enc(pe[t]));
            }
        }
        for (int i = tid; i < sc; i += 512) {
            unsigned ent = sbuf[b * SCAP + i];
            int loc = ent & 511;
            int eid = ent >> 9;
            int pos = atomicAdd(&cnt[loc], 1);
            esrc[rb + pos] = src[eid];
            const float* pe = &ea[(size_t)eid * DE];
            #pragma unroll
            for (int t = 0; t < DE; ++t) atomicMax(&emax[loc * DE + t], enc(pe[t]));
        }
        __syncthreads();
    }
    // coalesced eagg out (encoded; k_gemm decodes, ENC_NEGINF -> 0)
    for (int i = tid; i < (nend - nb) * DE; i += 512) eaggk[nb * DE + i] = emax[i];
}

// ---------------- gather-max: half-wave per node, raw bf16 maxima out ----------------
__global__ void k_agg(const unsigned* __restrict__ Xb, const int* __restrict__ rowptr,
                      const int* __restrict__ esrc, unsigned* __restrict__ Ab) {
    int n = blockIdx.x * 8 + (threadIdx.x >> 5);
    int lt = threadIdx.x & 31;
    if (n >= NN) return;
    int rs = rowptr[n], re = rowptr[n + 1];
    float m0 = NINF, m1 = NINF, p0 = NINF, p1 = NINF;
    int j = rs;
    for (; j + 16 <= re; j += 16) {
        unsigned v0 = Xb[(size_t)esrc[j + 0] * 32 + lt],  v1 = Xb[(size_t)esrc[j + 1] * 32 + lt];
        unsigned v2 = Xb[(size_t)esrc[j + 2] * 32 + lt],  v3 = Xb[(size_t)esrc[j + 3] * 32 + lt];
        unsigned v4 = Xb[(size_t)esrc[j + 4] * 32 + lt],  v5 = Xb[(size_t)esrc[j + 5] * 32 + lt];
        unsigned v6 = Xb[(size_t)esrc[j + 6] * 32 + lt],  v7 = Xb[(size_t)esrc[j + 7] * 32 + lt];
        unsigned v8 = Xb[(size_t)esrc[j + 8] * 32 + lt],  v9 = Xb[(size_t)esrc[j + 9] * 32 + lt];
        unsigned va = Xb[(size_t)esrc[j + 10] * 32 + lt], vb = Xb[(size_t)esrc[j + 11] * 32 + lt];
        unsigned vc = Xb[(size_t)esrc[j + 12] * 32 + lt], vd = Xb[(size_t)esrc[j + 13] * 32 + lt];
        unsigned ve = Xb[(size_t)esrc[j + 14] * 32 + lt], vf = Xb[(size_t)esrc[j + 15] * 32 + lt];
        m0 = fmaxf(m0, fmaxf(fmaxf(blo(v0), blo(v1)), fmaxf(blo(v2), blo(v3))));
        p0 = fmaxf(p0, fmaxf(fmaxf(blo(v4), blo(v5)), fmaxf(blo(v6), blo(v7))));
        m0 = fmaxf(m0, fmaxf(fmaxf(blo(v8), blo(v9)), fmaxf(blo(va), blo(vb))));
        p0 = fmaxf(p0, fmaxf(fmaxf(blo(vc), blo(vd)), fmaxf(blo(ve), blo(vf))));
        m1 = fmaxf(m1, fmaxf(fmaxf(bhi(v0), bhi(v1)), fmaxf(bhi(v2), bhi(v3))));
        p1 = fmaxf(p1, fmaxf(fmaxf(bhi(v4), bhi(v5)), fmaxf(bhi(v6), bhi(v7))));
        m1 = fmaxf(m1, fmaxf(fmaxf(bhi(v8), bhi(v9)), fmaxf(bhi(va), bhi(vb))));
        p1 = fmaxf(p1, fmaxf(fmaxf(bhi(vc), bhi(vd)), fmaxf(bhi(ve), bhi(vf))));
    }
    for (; j + 4 <= re; j += 4) {
        unsigned v0 = Xb[(size_t)esrc[j + 0] * 32 + lt], v1 = Xb[(size_t)esrc[j + 1] * 32 + lt];
        unsigned v2 = Xb[(size_t)esrc[j + 2] * 32 + lt], v3 = Xb[(size_t)esrc[j + 3] * 32 + lt];
        m0 = fmaxf(m0, fmaxf(blo(v0), blo(v1))); p0 = fmaxf(p0, fmaxf(blo(v2), blo(v3)));
        m1 = fmaxf(m1, fmaxf(bhi(v0), bhi(v1))); p1 = fmaxf(p1, fmaxf(bhi(v2), bhi(v3)));
    }
    for (; j < re; ++j) {
        unsigned v = Xb[(size_t)esrc[j] * 32 + lt];
        m0 = fmaxf(m0, blo(v)); m1 = fmaxf(m1, bhi(v));
    }
    m0 = fmaxf(m0, p0);
    m1 = fmaxf(m1, p1);
    Ab[(size_t)n * 32 + lt] = bfr(m0) | (bfr(m1) << 16);
}

// ---------------- GEMM: along-k LDS, float4-only reads, k-blocked x4 ----------------
// Ag[64][76]: cols 0..63 = node features, 64..69 = eagg, 70..71 = 0. Wl[72][68]: rows 70,71 = 0.
__launch_bounds__(256)
__global__ void k_gemm(const unsigned* __restrict__ Ab, const unsigned* __restrict__ eaggk,
                       const float* __restrict__ ss, int apply,
                       const float* __restrict__ W, const float* __restrict__ b,
                       unsigned* __restrict__ Hb, float* __restrict__ stats) {
    __shared__ float Wl[72][68];    // 19.1 KB
    __shared__ float Ag[64][76];    // 19.0 KB
    __shared__ float ls[128];

    int tid = threadIdx.x;
    int n0 = blockIdx.x * 64;

    // stage W (rows 70,71 zero); coalesced, conflict-free writes
    for (int i = tid; i < 72 * 64; i += 256) {
        int k = i >> 6, jj = i & 63;
        Wl[k][jj] = (k < FAN) ? W[k * 64 + jj] : 0.f;
    }
    // stage A (decode bf16 + prev-layer norm/relu), float2 writes, 2-way bank (free)
    for (int i = tid; i < 64 * 32; i += 256) {
        int r = i >> 5, c2 = i & 31;
        int n = n0 + r;
        unsigned wv = (n < NN) ? Ab[(size_t)n * 32 + c2] : 0xFF80FF80u;
        float a0 = blo(wv), a1 = bhi(wv);
        if (apply) {
            a0 = (a0 == NINF) ? 0.f : fmaxf(fmaf(a0, ss[2 * c2], ss[D + 2 * c2]), 0.f);
            a1 = (a1 == NINF) ? 0.f : fmaxf(fmaf(a1, ss[2 * c2 + 1], ss[D + 2 * c2 + 1]), 0.f);
        } else {
            a0 = (a0 == NINF) ? 0.f : a0;
            a1 = (a1 == NINF) ? 0.f : a1;
        }
        *(float2*)&Ag[r][2 * c2] = make_float2(a0, a1);
    }
    // stage eagg cols 64..69 (+ zero 70,71)
    for (int i = tid; i < 64 * 8; i += 256) {
        int r = i >> 3, c = i & 7;
        int n = n0 + r;
        float v = 0.f;
        if (c < DE && n < NN) {
            unsigned u = eaggk[n * DE + c];
            v = (u == ENC_NEGINF) ? 0.f : dec(u);
        }
        Ag[r][64 + c] = v;
    }
    if (tid < 128) ls[tid] = 0.f;
    __syncthreads();

    // thread (tr,tc): rows {tr, tr+16, tr+32, tr+48}, dims {4tc..4tc+3}
    int tr = tid >> 4, tc = tid & 15;
    int c0 = tc * 4;
    float acc[4][4];
    #pragma unroll
    for (int i = 0; i < 4; i++)
        #pragma unroll
        for (int jj = 0; jj < 4; jj++) acc[i][jj] = 0.f;

    for (int kb = 0; kb < 18; ++kb) {
        int k4 = kb * 4;
        float a[4][4], wr[4][4];
        *(float4*)&a[0][0] = *(const float4*)&Ag[tr +  0][k4];
        *(float4*)&a[1][0] = *(const float4*)&Ag[tr + 16][k4];
        *(float4*)&a[2][0] = *(const float4*)&Ag[tr + 32][k4];
        *(float4*)&a[3][0] = *(const float4*)&Ag[tr + 48][k4];
        *(float4*)&wr[0][0] = *(const float4*)&Wl[k4 + 0][c0];
        *(float4*)&wr[1][0] = *(const float4*)&Wl[k4 + 1][c0];
        *(float4*)&wr[2][0] = *(const float4*)&Wl[k4 + 2][c0];
        *(float4*)&wr[3][0] = *(const float4*)&Wl[k4 + 3][c0];
        #pragma unroll
        for (int kk = 0; kk < 4; ++kk)
            #pragma unroll
            for (int i = 0; i < 4; ++i)
                #pragma unroll
                for (int jj = 0; jj < 4; ++jj)
                    acc[i][jj] = fmaf(a[i][kk], wr[kk][jj], acc[i][jj]);
    }

    float4 bb = *(const float4*)&b[c0];
    float cs[4] = {0.f, 0.f, 0.f, 0.f};
    float cq[4] = {0.f, 0.f, 0.f, 0.f};
    #pragma unroll
    for (int i = 0; i < 4; i++) {
        int n = n0 + tr + 16 * i;
        if (n < NN) {
            float ox = acc[i][0] + bb.x, oy = acc[i][1] + bb.y;
            float oz = acc[i][2] + bb.z, ow = acc[i][3] + bb.w;
            uint2 pk = make_uint2(bfr(ox) | (bfr(oy) << 16), bfr(oz) | (bfr(ow) << 16));
            *(uint2*)&Hb[(size_t)n * 32 + 2 * tc] = pk;
            cs[0] += ox; cs[1] += oy; cs[2] += oz; cs[3] += ow;
            cq[0] += ox * ox; cq[1] += oy * oy; cq[2] += oz * oz; cq[3] += ow * ow;
        }
    }
    #pragma unroll
    for (int jj = 0; jj < 4; jj++) {
        atomicAdd(&ls[c0 + jj], cs[jj]);
        atomicAdd(&ls[64 + c0 + jj], cq[jj]);
    }
    __syncthreads();
    if (tid < 128) atomicAdd(&stats[tid], ls[tid]);
}

__global__ void k_finalize_stats(const float* __restrict__ stats, const float* __restrict__ g,
                                 const float* __restrict__ beta, float* __restrict__ ss) {
    int j = threadIdx.x;  // 64 threads
    float mean = stats[j] * (1.0f / NN);
    float var = stats[64 + j] * (1.0f / NN) - mean * mean;
    float sc = rsqrtf(var + EPS) * g[j];
    ss[j] = sc;
    ss[64 + j] = beta[j] - mean * sc;
}

// graph offsets from sorted batch
__global__ void k_gptr(const int* __restrict__ batch, int* __restrict__ gptr) {
    int i = blockIdx.x * 256 + threadIdx.x;
    if (i >= NN) return;
    int b = batch[i];
    int prev = (i == 0) ? -1 : batch[i - 1];
    for (int g = prev + 1; g <= b; ++g) gptr[g] = i;
    if (i == NN - 1) {
        for (int g = b + 1; g <= NG; ++g) gptr[g] = NN;
    }
}

// pool(gather) + norm/relu + dot: half-wave per graph
__global__ void k_gfinal(const unsigned* __restrict__ Hb, const int* __restrict__ gptr,
                         const float* __restrict__ ss, const float* __restrict__ lw,
                         const float* __restrict__ lb, float* __restrict__ out) {
    int g = blockIdx.x * 8 + (threadIdx.x >> 5);
    int lt = threadIdx.x & 31;
    if (g >= NG) return;
    int rs = gptr[g], re = gptr[g + 1];
    float m0 = NINF, m1 = NINF, p0 = NINF, p1 = NINF;
    int n = rs;
    for (; n + 4 <= re; n += 4) {
        unsigned v0 = Hb[(size_t)(n + 0) * 32 + lt];
        unsigned v1 = Hb[(size_t)(n + 1) * 32 + lt];
        unsigned v2 = Hb[(size_t)(n + 2) * 32 + lt];
        unsigned v3 = Hb[(size_t)(n + 3) * 32 + lt];
        m0 = fmaxf(m0, fmaxf(blo(v0), blo(v1))); m1 = fmaxf(m1, fmaxf(bhi(v0), bhi(v1)));
        p0 = fmaxf(p0, fmaxf(blo(v2), blo(v3))); p1 = fmaxf(p1, fmaxf(bhi(v2), bhi(v3)));
    }
    for (; n < re; ++n) {
        unsigned v = Hb[(size_t)n * 32 + lt];
        m0 = fmaxf(m0, blo(v)); m1 = fmaxf(m1, bhi(v));
    }
    m0 = fmaxf(m0, p0);
    m1 = fmaxf(m1, p1);
    float a0 = (m0 == NINF) ? 0.f : fmaxf(fmaf(m0, ss[2 * lt], ss[D + 2 * lt]), 0.f);
    float a1 = (m1 == NINF) ? 0.f : fmaxf(fmaf(m1, ss[2 * lt + 1], ss[D + 2 * lt + 1]), 0.f);
    float p = fmaf(a0, lw[2 * lt], a1 * lw[2 * lt + 1]);
    #pragma unroll
    for (int off = 1; off < 32; off <<= 1) p += __shfl_xor(p, off);
    if (lt == 0) out[g] = p + lb[0];
}

extern "C" void kernel_launch(void* const* d_in, const int* in_sizes, int n_in,
                              void* d_out, int out_size, void* d_ws, size_t ws_size,
                              hipStream_t stream) {
    const float* x     = (const float*)d_in[0];
    const int*   ei    = (const int*)d_in[1];
    const float* ea    = (const float*)d_in[2];
    const int*   batch = (const int*)d_in[3];
    const float* Wp[3] = {(const float*)d_in[4],  (const float*)d_in[8],  (const float*)d_in[12]};
    const float* bp[3] = {(const float*)d_in[5],  (const float*)d_in[9],  (const float*)d_in[13]};
    const float* gp[3] = {(const float*)d_in[6],  (const float*)d_in[10], (const float*)d_in[14]};
    const float* tp[3] = {(const float*)d_in[7],  (const float*)d_in[11], (const float*)d_in[15]};
    const float* lw    = (const float*)d_in[16];
    const float* lb    = (const float*)d_in[17];
    float* out = (float*)d_out;

    const int* src = ei;
    const int* dst = ei + NE;

    // workspace layout (u32 words; fill targets 16B-aligned)
    unsigned* w = (unsigned*)d_ws;
    int*      rowptr  = (int*)w;                   // 100004
    int*      esrc    = (int*)(w + 100004);        // 1600000
    unsigned* eaggk   = w + 1700004;               // 600000
    float*    stats   = (float*)(w + 2300004);     // 128
    float*    ss      = (float*)(w + 2300132);     // 128
    int*      gptr    = (int*)(w + 2300260);       // 1032
    int*      scnt    = (int*)(w + 2301292);       // 256
    int*      buktot  = (int*)(w + 2301548);       // 256
    int*      bukbase = (int*)(w + 2301804);       // 256
    // big region: Xb0/Hb1/Hb2 for layers; CSR scratch aliases it (dead before k_cast)
    unsigned* Xb0     = w + 2302064;               // 3200000
    unsigned* Hb1     = w + 5502064;               // 3200000
    unsigned* Hb2     = w + 8702064;               // 3200000 (end 11902064 = 47.6 MB)
    int*      cntA    = (int*)Xb0;                 // 196000 (alias)
    unsigned* gbuck   = w + 2502064;               // 4704000 (alias)
    unsigned* sbuf    = w + 7206064;               // 200704 (alias)

    // --- zero spill counters ---
    k_fill_u32x4<<<1, 64, 0, stream>>>((uint4*)scnt, 0u, 64);

    // --- CSR build + edge_attr seg-max, all via deterministic-slot binning ---
    k_binA<<<NBLKA, 256, 0, stream>>>(dst, gbuck, cntA, scnt, sbuf);
    k_buksum<<<NBUK, 256, 0, stream>>>(cntA, scnt, buktot);
    k_bukscan<<<1, 256, 0, stream>>>(buktot, bukbase);
    k_binB<<<NBUK, 512, 0, stream>>>(gbuck, cntA, scnt, sbuf, bukbase, src, ea,
                                     rowptr, esrc, eaggk);

    // --- bf16 cast (AFTER binB: Xb0 aliases CSR scratch) + graph offsets ---
    k_cast<<<(NN * 16 + 255) / 256, 256, 0, stream>>>((const float4*)x, (uint2*)Xb0, NN * 16);
    k_gptr<<<(NN + 255) / 256, 256, 0, stream>>>(batch, gptr);

    // --- 3 layers: agg (raw bf16 maxima) -> gemm (decode + fused prev norm/relu) ---
    const unsigned* ain[3] = {Xb0, Hb1, Hb2};
    unsigned* abuf[3] = {Hb2, Xb0, Hb1};
    unsigned* hbuf[3] = {Hb1, Hb2, Xb0};
    for (int l = 0; l < 3; ++l) {
        k_agg<<<NN / 8, 256, 0, stream>>>(ain[l], rowptr, esrc, abuf[l]);
        k_fill_u32x4<<<1, 32, 0, stream>>>((uint4*)stats, 0u, 32);
        k_gemm<<<(NN + 63) / 64, 256, 0, stream>>>(abuf[l], eaggk, ss, l > 0 ? 1 : 0,
                                                   Wp[l], bp[l], hbuf[l], stats);
        k_finalize_stats<<<1, 64, 0, stream>>>(stats, gp[l], tp[l], ss);
    }

    // --- pooled gather + final norm/relu/dot ---
    k_gfinal<<<NG / 8, 256, 0, stream>>>(Xb0, gptr, ss, lw, lb, out);
}

// Round 9
// 484.241 us; speedup vs baseline: 1.0167x; 1.0167x over previous
//
#include <hip/hip_runtime.h>

#define NN 100000
#define NE 1600000
#define NG 1024
#define D 64
#define DE 6
#define FAN 70
#define EPS 1e-5f

#define ENC_NEGINF 0x007FFFFFu
#define NINF (-__builtin_inff())

#define NBUK 196      // dst buckets of 512 nodes
#define TILE 1600     // edges per binA block
#define NBLKA 1000    // NE / TILE
#define ACAP 24       // per-(bucket,block) deterministic slot capacity (lambda=8.16)
#define SCAP 1024     // per-bucket spill capacity (rare path)
#define BCAP 10240    // binB LDS esrc capacity
#define NBLKG 782     // gemm blocks: 128 rows each (782*128 = 100096)

__device__ __forceinline__ unsigned enc(float f) {
    unsigned u = __float_as_uint(f);
    return (u & 0x80000000u) ? ~u : (u | 0x80000000u);
}
__device__ __forceinline__ float dec(unsigned u) {
    return (u & 0x80000000u) ? __uint_as_float(u & 0x7FFFFFFFu) : __uint_as_float(~u);
}
__device__ __forceinline__ unsigned bfr(float f) {   // fp32 -> bf16 bits, RNE
    unsigned u = __float_as_uint(f);
    return (u + 0x7FFFu + ((u >> 16) & 1)) >> 16;
}
__device__ __forceinline__ float blo(unsigned w) { return __uint_as_float(w << 16); }
__device__ __forceinline__ float bhi(unsigned w) { return __uint_as_float(w & 0xFFFF0000u); }

__global__ void k_fill_u32x4(uint4* __restrict__ p, unsigned v, int n4) {
    int i = blockIdx.x * 256 + threadIdx.x;
    if (i < n4) p[i] = make_uint4(v, v, v, v);
}

// fp32 [NN][64] -> bf16-packed [NN][32] u32
__global__ void k_cast(const float4* __restrict__ in, uint2* __restrict__ out, int n4) {
    int i = blockIdx.x * 256 + threadIdx.x;
    if (i < n4) {
        float4 v = in[i];
        out[i] = make_uint2(bfr(v.x) | (bfr(v.y) << 16), bfr(v.z) | (bfr(v.w) << 16));
    }
}

// pass A: deterministic slots gbuck[b][blk][ACAP], entries (eid<<9 | dst&511)
__launch_bounds__(256)
__global__ void k_binA(const int* __restrict__ dst,
                       unsigned* __restrict__ gbuck, int* __restrict__ cntA,
                       int* __restrict__ scnt, unsigned* __restrict__ sbuf) {
    __shared__ int cnt[NBUK];
    int tid = threadIdx.x, blk = blockIdx.x;
    for (int i = tid; i < NBUK; i += 256) cnt[i] = 0;
    __syncthreads();
    int e0 = blk * TILE;
    int e1 = min(e0 + TILE, NE);
    for (int e = e0 + tid; e < e1; e += 256) {
        int d = dst[e];
        int b = d >> 9;
        unsigned ent = ((unsigned)e << 9) | (unsigned)(d & 511);
        int pos = atomicAdd(&cnt[b], 1);
        if (pos < ACAP) gbuck[((size_t)b * NBLKA + blk) * ACAP + pos] = ent;
        else {  // rare spill
            int sp = atomicAdd(&scnt[b], 1);
            if (sp < SCAP) sbuf[b * SCAP + sp] = ent;
        }
    }
    __syncthreads();
    for (int i = tid; i < NBUK; i += 256) cntA[blk * NBUK + i] = min(cnt[i], ACAP);
}

// per-bucket totals
__global__ void k_buksum(const int* __restrict__ cntA, const int* __restrict__ scnt,
                         int* __restrict__ buktot) {
    __shared__ int red[256];
    int b = blockIdx.x, tid = threadIdx.x;
    int sum = 0;
    for (int blk = tid; blk < NBLKA; blk += 256) sum += cntA[blk * NBUK + b];
    red[tid] = sum;
    __syncthreads();
    for (int off = 128; off > 0; off >>= 1) {
        if (tid < off) red[tid] += red[tid + off];
        __syncthreads();
    }
    if (tid == 0) buktot[b] = red[0] + min(scnt[b], SCAP);
}

// exclusive scan of 196 bucket totals
__global__ void k_bukscan(const int* __restrict__ buktot, int* __restrict__ bukbase) {
    __shared__ int s[256];
    int t = threadIdx.x;
    int c = (t < NBUK) ? buktot[t] : 0;
    s[t] = c;
    __syncthreads();
    for (int off = 1; off < 256; off <<= 1) {
        int y = (t >= off) ? s[t - off] : 0;
        __syncthreads();
        s[t] += y;
        __syncthreads();
    }
    if (t < NBUK) bukbase[t] = s[t] - c;
}

// pass B: per bucket — count+scan -> rowptr; scatter esrc via LDS; eagg via LDS atomicMax
__launch_bounds__(512)
__global__ void k_binB(const unsigned* __restrict__ gbuck, const int* __restrict__ cntA,
                       const int* __restrict__ scnt, const unsigned* __restrict__ sbuf,
                       const int* __restrict__ bukbase,
                       const int* __restrict__ src, const float* __restrict__ ea,
                       int* __restrict__ rowptr, int* __restrict__ esrc,
                       unsigned* __restrict__ eaggk) {
    __shared__ int cnt[512];
    __shared__ int base[512];
    __shared__ unsigned el[BCAP];            // 40 KB
    __shared__ unsigned emax[512 * DE];      // 12 KB
    int b = blockIdx.x, tid = threadIdx.x;
    int nb = b << 9;
    int nend = min(nb + 512, NN);
    cnt[tid] = 0;
    for (int i = tid; i < 512 * DE; i += 512) emax[i] = ENC_NEGINF;
    __syncthreads();
    int sc = min(scnt[b], SCAP);
    // pass 1: per-node counts
    for (int blk = tid; blk < NBLKA; blk += 512) {
        int c = cntA[blk * NBUK + b];
        const unsigned* p = &gbuck[((size_t)b * NBLKA + blk) * ACAP];
        for (int i = 0; i < c; ++i) atomicAdd(&cnt[p[i] & 511], 1);
    }
    for (int i = tid; i < sc; i += 512) atomicAdd(&cnt[sbuf[b * SCAP + i] & 511], 1);
    __syncthreads();
    // inclusive scan of 512 counts
    int v = cnt[tid];
    base[tid] = v;
    __syncthreads();
    for (int off = 1; off < 512; off <<= 1) {
        int y = (tid >= off) ? base[tid - off] : 0;
        __syncthreads();
        base[tid] += y;
        __syncthreads();
    }
    int excl = base[tid] - v;
    int rb = bukbase[b];
    if (nb + tid < NN) rowptr[nb + tid] = rb + excl;
    if (b == NBUK - 1 && tid == 0) rowptr[NN] = NE;
    int regsz = base[511];
    __syncthreads();
    cnt[tid] = excl;   // reuse as cursor
    __syncthreads();
    // pass 2: scatter + edge_attr seg-max (LDS)
    if (regsz <= BCAP) {
        for (int blk = tid; blk < NBLKA; blk += 512) {
            int c = cntA[blk * NBUK + b];
            const unsigned* p = &gbuck[((size_t)b * NBLKA + blk) * ACAP];
            for (int i = 0; i < c; ++i) {
                unsigned ent = p[i];
                int loc = ent & 511;
                int eid = ent >> 9;
                int pos = atomicAdd(&cnt[loc], 1);
                el[pos] = (unsigned)src[eid];
                const float* pe = &ea[(size_t)eid * DE];
                #pragma unroll
                for (int t = 0; t < DE; ++t) atomicMax(&emax[loc * DE + t], enc(pe[t]));
            }
        }
        for (int i = tid; i < sc; i += 512) {
            unsigned ent = sbuf[b * SCAP + i];
            int loc = ent & 511;
            int eid = ent >> 9;
            int pos = atomicAdd(&cnt[loc], 1);
            el[pos] = (unsigned)src[eid];
            const float* pe = &ea[(size_t)eid * DE];
            #pragma unroll
            for (int t = 0; t < DE; ++t) atomicMax(&emax[loc * DE + t], enc(pe[t]));
        }
        __syncthreads();
        for (int i = tid; i < regsz; i += 512) esrc[rb + i] = (int)el[i];
    } else {  // capacity fallback: direct global scatter (correct, slower)
        for (int blk = tid; blk < NBLKA; blk += 512) {
            int c = cntA[blk * NBUK + b];
            const unsigned* p = &gbuck[((size_t)b * NBLKA + blk) * ACAP];
            for (int i = 0; i < c; ++i) {
                unsigned ent = p[i];
                int loc = ent & 511;
                int eid = ent >> 9;
                int pos = atomicAdd(&cnt[loc], 1);
                esrc[rb + pos] = src[eid];
                const float* pe = &ea[(size_t)eid * DE];
                #pragma unroll
                for (int t = 0; t < DE; ++t) atomicMax(&emax[loc * DE + t], enc(pe[t]));
            }
        }
        for (int i = tid; i < sc; i += 512) {
            unsigned ent = sbuf[b * SCAP + i];
            int loc = ent & 511;
            int eid = ent >> 9;
            int pos = atomicAdd(&cnt[loc], 1);
            esrc[rb + pos] = src[eid];
            const float* pe = &ea[(size_t)eid * DE];
            #pragma unroll
            for (int t = 0; t < DE; ++t) atomicMax(&emax[loc * DE + t], enc(pe[t]));
        }
        __syncthreads();
    }
    // coalesced eagg out (encoded; k_gemm decodes, ENC_NEGINF -> 0)
    for (int i = tid; i < (nend - nb) * DE; i += 512) eaggk[nb * DE + i] = emax[i];
}

// ---------------- gather-max: half-wave per node, raw bf16 maxima out ----------------
__global__ void k_agg(const unsigned* __restrict__ Xb, const int* __restrict__ rowptr,
                      const int* __restrict__ esrc, unsigned* __restrict__ Ab) {
    int n = blockIdx.x * 8 + (threadIdx.x >> 5);
    int lt = threadIdx.x & 31;
    if (n >= NN) return;
    int rs = rowptr[n], re = rowptr[n + 1];
    float m0 = NINF, m1 = NINF, p0 = NINF, p1 = NINF;
    int j = rs;
    for (; j + 16 <= re; j += 16) {
        unsigned v0 = Xb[(size_t)esrc[j + 0] * 32 + lt],  v1 = Xb[(size_t)esrc[j + 1] * 32 + lt];
        unsigned v2 = Xb[(size_t)esrc[j + 2] * 32 + lt],  v3 = Xb[(size_t)esrc[j + 3] * 32 + lt];
        unsigned v4 = Xb[(size_t)esrc[j + 4] * 32 + lt],  v5 = Xb[(size_t)esrc[j + 5] * 32 + lt];
        unsigned v6 = Xb[(size_t)esrc[j + 6] * 32 + lt],  v7 = Xb[(size_t)esrc[j + 7] * 32 + lt];
        unsigned v8 = Xb[(size_t)esrc[j + 8] * 32 + lt],  v9 = Xb[(size_t)esrc[j + 9] * 32 + lt];
        unsigned va = Xb[(size_t)esrc[j + 10] * 32 + lt], vb = Xb[(size_t)esrc[j + 11] * 32 + lt];
        unsigned vc = Xb[(size_t)esrc[j + 12] * 32 + lt], vd = Xb[(size_t)esrc[j + 13] * 32 + lt];
        unsigned ve = Xb[(size_t)esrc[j + 14] * 32 + lt], vf = Xb[(size_t)esrc[j + 15] * 32 + lt];
        m0 = fmaxf(m0, fmaxf(fmaxf(blo(v0), blo(v1)), fmaxf(blo(v2), blo(v3))));
        p0 = fmaxf(p0, fmaxf(fmaxf(blo(v4), blo(v5)), fmaxf(blo(v6), blo(v7))));
        m0 = fmaxf(m0, fmaxf(fmaxf(blo(v8), blo(v9)), fmaxf(blo(va), blo(vb))));
        p0 = fmaxf(p0, fmaxf(fmaxf(blo(vc), blo(vd)), fmaxf(blo(ve), blo(vf))));
        m1 = fmaxf(m1, fmaxf(fmaxf(bhi(v0), bhi(v1)), fmaxf(bhi(v2), bhi(v3))));
        p1 = fmaxf(p1, fmaxf(fmaxf(bhi(v4), bhi(v5)), fmaxf(bhi(v6), bhi(v7))));
        m1 = fmaxf(m1, fmaxf(fmaxf(bhi(v8), bhi(v9)), fmaxf(bhi(va), bhi(vb))));
        p1 = fmaxf(p1, fmaxf(fmaxf(bhi(vc), bhi(vd)), fmaxf(bhi(ve), bhi(vf))));
    }
    for (; j + 4 <= re; j += 4) {
        unsigned v0 = Xb[(size_t)esrc[j + 0] * 32 + lt], v1 = Xb[(size_t)esrc[j + 1] * 32 + lt];
        unsigned v2 = Xb[(size_t)esrc[j + 2] * 32 + lt], v3 = Xb[(size_t)esrc[j + 3] * 32 + lt];
        m0 = fmaxf(m0, fmaxf(blo(v0), blo(v1))); p0 = fmaxf(p0, fmaxf(blo(v2), blo(v3)));
        m1 = fmaxf(m1, fmaxf(bhi(v0), bhi(v1))); p1 = fmaxf(p1, fmaxf(bhi(v2), bhi(v3)));
    }
    for (; j < re; ++j) {
        unsigned v = Xb[(size_t)esrc[j] * 32 + lt];
        m0 = fmaxf(m0, blo(v)); m1 = fmaxf(m1, bhi(v));
    }
    m0 = fmaxf(m0, p0);
    m1 = fmaxf(m1, p1);
    Ab[(size_t)n * 32 + lt] = bfr(m0) | (bfr(m1) << 16);
}

// ---------------- GEMM: 128 rows/block, per-block stats stores (no global atomics) ----
// Ag[128][76]: cols 0..63 = node features, 64..69 = eagg, 70..71 = 0. Wl[72][68]: rows 70,71 = 0.
__launch_bounds__(512)
__global__ void k_gemm(const unsigned* __restrict__ Ab, const unsigned* __restrict__ eaggk,
                       const float* __restrict__ ss, int apply,
                       const float* __restrict__ W, const float* __restrict__ b,
                       unsigned* __restrict__ Hb, float* __restrict__ pstats) {
    __shared__ float Wl[72][68];     // 19.1 KB
    __shared__ float Ag[128][76];    // 38.9 KB
    __shared__ float ls[128];

    int tid = threadIdx.x;
    int n0 = blockIdx.x * 128;

    // stage W as float4 (rows 70,71 zero)
    const float4* W4 = (const float4*)W;
    for (int i = tid; i < 72 * 16; i += 512) {
        int k = i >> 4, j4 = i & 15;
        float4 v = (k < FAN) ? W4[i] : make_float4(0.f, 0.f, 0.f, 0.f);
        *(float4*)&Wl[k][j4 * 4] = v;
    }
    // stage A (decode bf16 + prev-layer norm/relu): uint2 loads, float4 writes
    const uint2* Ab2 = (const uint2*)Ab;
    for (int i = tid; i < 128 * 16; i += 512) {
        int r = i >> 4, c4 = i & 15;     // c4: group of 4 dims (2 packed words)
        int n = n0 + r;
        uint2 wv = (n < NN) ? Ab2[(size_t)n * 16 + c4] : make_uint2(0xFF80FF80u, 0xFF80FF80u);
        float a0 = blo(wv.x), a1 = bhi(wv.x), a2 = blo(wv.y), a3 = bhi(wv.y);
        if (apply) {
            int c = 4 * c4;
            a0 = (a0 == NINF) ? 0.f : fmaxf(fmaf(a0, ss[c + 0], ss[D + c + 0]), 0.f);
            a1 = (a1 == NINF) ? 0.f : fmaxf(fmaf(a1, ss[c + 1], ss[D + c + 1]), 0.f);
            a2 = (a2 == NINF) ? 0.f : fmaxf(fmaf(a2, ss[c + 2], ss[D + c + 2]), 0.f);
            a3 = (a3 == NINF) ? 0.f : fmaxf(fmaf(a3, ss[c + 3], ss[D + c + 3]), 0.f);
        } else {
            a0 = (a0 == NINF) ? 0.f : a0;
            a1 = (a1 == NINF) ? 0.f : a1;
            a2 = (a2 == NINF) ? 0.f : a2;
            a3 = (a3 == NINF) ? 0.f : a3;
        }
        *(float4*)&Ag[r][4 * c4] = make_float4(a0, a1, a2, a3);
    }
    // stage eagg cols 64..69 (+ zero 70,71)
    for (int i = tid; i < 128 * 8; i += 512) {
        int r = i >> 3, c = i & 7;
        int n = n0 + r;
        float v = 0.f;
        if (c < DE && n < NN) {
            unsigned u = eaggk[n * DE + c];
            v = (u == ENC_NEGINF) ? 0.f : dec(u);
        }
        Ag[r][64 + c] = v;
    }
    if (tid < 128) ls[tid] = 0.f;
    __syncthreads();

    // thread (tr,tc): rows {tr, tr+32, tr+64, tr+96}, dims {4tc..4tc+3}
    int tr = tid >> 4, tc = tid & 15;
    int c0 = tc * 4;
    float acc[4][4];
    #pragma unroll
    for (int i = 0; i < 4; i++)
        #pragma unroll
        for (int jj = 0; jj < 4; jj++) acc[i][jj] = 0.f;

    for (int kb = 0; kb < 18; ++kb) {
        int k4 = kb * 4;
        float a[4][4], wr[4][4];
        *(float4*)&a[0][0] = *(const float4*)&Ag[tr +  0][k4];
        *(float4*)&a[1][0] = *(const float4*)&Ag[tr + 32][k4];
        *(float4*)&a[2][0] = *(const float4*)&Ag[tr + 64][k4];
        *(float4*)&a[3][0] = *(const float4*)&Ag[tr + 96][k4];
        *(float4*)&wr[0][0] = *(const float4*)&Wl[k4 + 0][c0];
        *(float4*)&wr[1][0] = *(const float4*)&Wl[k4 + 1][c0];
        *(float4*)&wr[2][0] = *(const float4*)&Wl[k4 + 2][c0];
        *(float4*)&wr[3][0] = *(const float4*)&Wl[k4 + 3][c0];
        #pragma unroll
        for (int kk = 0; kk < 4; ++kk)
            #pragma unroll
            for (int i = 0; i < 4; ++i)
                #pragma unroll
                for (int jj = 0; jj < 4; ++jj)
                    acc[i][jj] = fmaf(a[i][kk], wr[kk][jj], acc[i][jj]);
    }

    float4 bb = *(const float4*)&b[c0];
    float cs[4] = {0.f, 0.f, 0.f, 0.f};
    float cq[4] = {0.f, 0.f, 0.f, 0.f};
    #pragma unroll
    for (int i = 0; i < 4; i++) {
        int n = n0 + tr + 32 * i;
        if (n < NN) {
            float ox = acc[i][0] + bb.x, oy = acc[i][1] + bb.y;
            float oz = acc[i][2] + bb.z, ow = acc[i][3] + bb.w;
            uint2 pk = make_uint2(bfr(ox) | (bfr(oy) << 16), bfr(oz) | (bfr(ow) << 16));
            *(uint2*)&Hb[(size_t)n * 32 + 2 * tc] = pk;
            cs[0] += ox; cs[1] += oy; cs[2] += oz; cs[3] += ow;
            cq[0] += ox * ox; cq[1] += oy * oy; cq[2] += oz * oz; cq[3] += ow * ow;
        }
    }
    #pragma unroll
    for (int jj = 0; jj < 4; jj++) {
        atomicAdd(&ls[c0 + jj], cs[jj]);          // LDS only
        atomicAdd(&ls[64 + c0 + jj], cq[jj]);
    }
    __syncthreads();
    if (tid < 128) pstats[(size_t)blockIdx.x * 128 + tid] = ls[tid];  // coalesced store
}

// reduce per-block stats + finalize scale/shift (single block, 1024 threads)
__global__ void k_redfin(const float* __restrict__ pstats, const float* __restrict__ g,
                         const float* __restrict__ beta, float* __restrict__ ss) {
    __shared__ float red[8][128];
    __shared__ float tot[128];
    int tid = threadIdx.x;
    int j = tid & 127, seg = tid >> 7;
    float s = 0.f;
    for (int blk = seg; blk < NBLKG; blk += 8) s += pstats[(size_t)blk * 128 + j];
    red[seg][j] = s;
    __syncthreads();
    if (tid < 128) {
        float t = 0.f;
        #pragma unroll
        for (int k = 0; k < 8; ++k) t += red[k][tid];
        tot[tid] = t;
    }
    __syncthreads();
    if (tid < 64) {
        float mean = tot[tid] * (1.0f / NN);
        float var = tot[64 + tid] * (1.0f / NN) - mean * mean;
        float sc = rsqrtf(var + EPS) * g[tid];
        ss[tid] = sc;
        ss[64 + tid] = beta[tid] - mean * sc;
    }
}

// graph offsets from sorted batch
__global__ void k_gptr(const int* __restrict__ batch, int* __restrict__ gptr) {
    int i = blockIdx.x * 256 + threadIdx.x;
    if (i >= NN) return;
    int b = batch[i];
    int prev = (i == 0) ? -1 : batch[i - 1];
    for (int g = prev + 1; g <= b; ++g) gptr[g] = i;
    if (i == NN - 1) {
        for (int g = b + 1; g <= NG; ++g) gptr[g] = NN;
    }
}

// pool(gather) + norm/relu + dot: half-wave per graph
__global__ void k_gfinal(const unsigned* __restrict__ Hb, const int* __restrict__ gptr,
                         const float* __restrict__ ss, const float* __restrict__ lw,
                         const float* __restrict__ lb, float* __restrict__ out) {
    int g = blockIdx.x * 8 + (threadIdx.x >> 5);
    int lt = threadIdx.x & 31;
    if (g >= NG) return;
    int rs = gptr[g], re = gptr[g + 1];
    float m0 = NINF, m1 = NINF, p0 = NINF, p1 = NINF;
    int n = rs;
    for (; n + 4 <= re; n += 4) {
        unsigned v0 = Hb[(size_t)(n + 0) * 32 + lt];
        unsigned v1 = Hb[(size_t)(n + 1) * 32 + lt];
        unsigned v2 = Hb[(size_t)(n + 2) * 32 + lt];
        unsigned v3 = Hb[(size_t)(n + 3) * 32 + lt];
        m0 = fmaxf(m0, fmaxf(blo(v0), blo(v1))); m1 = fmaxf(m1, fmaxf(bhi(v0), bhi(v1)));
        p0 = fmaxf(p0, fmaxf(blo(v2), blo(v3))); p1 = fmaxf(p1, fmaxf(bhi(v2), bhi(v3)));
    }
    for (; n < re; ++n) {
        unsigned v = Hb[(size_t)n * 32 + lt];
        m0 = fmaxf(m0, blo(v)); m1 = fmaxf(m1, bhi(v));
    }
    m0 = fmaxf(m0, p0);
    m1 = fmaxf(m1, p1);
    float a0 = (m0 == NINF) ? 0.f : fmaxf(fmaf(m0, ss[2 * lt], ss[D + 2 * lt]), 0.f);
    float a1 = (m1 == NINF) ? 0.f : fmaxf(fmaf(m1, ss[2 * lt + 1], ss[D + 2 * lt + 1]), 0.f);
    float p = fmaf(a0, lw[2 * lt], a1 * lw[2 * lt + 1]);
    #pragma unroll
    for (int off = 1; off < 32; off <<= 1) p += __shfl_xor(p, off);
    if (lt == 0) out[g] = p + lb[0];
}

extern "C" void kernel_launch(void* const* d_in, const int* in_sizes, int n_in,
                              void* d_out, int out_size, void* d_ws, size_t ws_size,
                              hipStream_t stream) {
    const float* x     = (const float*)d_in[0];
    const int*   ei    = (const int*)d_in[1];
    const float* ea    = (const float*)d_in[2];
    const int*   batch = (const int*)d_in[3];
    const float* Wp[3] = {(const float*)d_in[4],  (const float*)d_in[8],  (const float*)d_in[12]};
    const float* bp[3] = {(const float*)d_in[5],  (const float*)d_in[9],  (const float*)d_in[13]};
    const float* gp[3] = {(const float*)d_in[6],  (const float*)d_in[10], (const float*)d_in[14]};
    const float* tp[3] = {(const float*)d_in[7],  (const float*)d_in[11], (const float*)d_in[15]};
    const float* lw    = (const float*)d_in[16];
    const float* lb    = (const float*)d_in[17];
    float* out = (float*)d_out;

    const int* src = ei;
    const int* dst = ei + NE;

    // workspace layout (u32 words; fill targets 16B-aligned)
    unsigned* w = (unsigned*)d_ws;
    int*      rowptr  = (int*)w;                   // 100004
    int*      esrc    = (int*)(w + 100004);        // 1600000
    unsigned* eaggk   = w + 1700004;               // 600000
    float*    ss      = (float*)(w + 2300004);     // 128
    int*      gptr    = (int*)(w + 2300132);       // 1032
    int*      scnt    = (int*)(w + 2301164);       // 256
    int*      buktot  = (int*)(w + 2301420);       // 256
    int*      bukbase = (int*)(w + 2301676);       // 256
    float*    pstats  = (float*)(w + 2301932);     // NBLKG*128 = 100096 (+pad)
    // big region: Xb0/Hb1/Hb2 for layers; CSR scratch aliases it (dead before k_cast)
    unsigned* Xb0     = w + 2402128;               // 3200000
    unsigned* Hb1     = w + 5602128;               // 3200000
    unsigned* Hb2     = w + 8802128;               // 3200000 (end 12002128 = 48.0 MB)
    int*      cntA    = (int*)Xb0;                 // 196000 (alias)
    unsigned* gbuck   = w + 2602128;               // 4704000 (alias)
    unsigned* sbuf    = w + 7306128;               // 200704 (alias)

    // --- zero spill counters ---
    k_fill_u32x4<<<1, 64, 0, stream>>>((uint4*)scnt, 0u, 64);

    // --- CSR build + edge_attr seg-max, all via deterministic-slot binning ---
    k_binA<<<NBLKA, 256, 0, stream>>>(dst, gbuck, cntA, scnt, sbuf);
    k_buksum<<<NBUK, 256, 0, stream>>>(cntA, scnt, buktot);
    k_bukscan<<<1, 256, 0, stream>>>(buktot, bukbase);
    k_binB<<<NBUK, 512, 0, stream>>>(gbuck, cntA, scnt, sbuf, bukbase, src, ea,
                                     rowptr, esrc, eaggk);

    // --- bf16 cast (AFTER binB: Xb0 aliases CSR scratch) + graph offsets ---
    k_cast<<<(NN * 16 + 255) / 256, 256, 0, stream>>>((const float4*)x, (uint2*)Xb0, NN * 16);
    k_gptr<<<(NN + 255) / 256, 256, 0, stream>>>(batch, gptr);

    // --- 3 layers: agg (raw bf16 maxima) -> gemm (decode + fused prev norm/relu) ---
    const unsigned* ain[3] = {Xb0, Hb1, Hb2};
    unsigned* abuf[3] = {Hb2, Xb0, Hb1};
    unsigned* hbuf[3] = {Hb1, Hb2, Xb0};
    for (int l = 0; l < 3; ++l) {
        k_agg<<<NN / 8, 256, 0, stream>>>(ain[l], rowptr, esrc, abuf[l]);
        k_gemm<<<NBLKG, 512, 0, stream>>>(abuf[l], eaggk, ss, l > 0 ? 1 : 0,
                                          Wp[l], bp[l], hbuf[l], pstats);
        k_redfin<<<1, 1024, 0, stream>>>(pstats, gp[l], tp[l], ss);
    }

    // --- pooled gather + final norm/relu/dot ---
    k_gfinal<<<NG / 8, 256, 0, stream>>>(Xb0, gptr, ss, lw, lb, out);
}

// Round 10
// 482.365 us; speedup vs baseline: 1.0206x; 1.0039x over previous
//
#include <hip/hip_runtime.h>

#define NN 100000
#define NE 1600000
#define NG 1024
#define D 64
#define DE 6
#define FAN 70
#define EPS 1e-5f

#define ENC_NEGINF 0x007FFFFFu
#define NINF (-__builtin_inff())

#define NBUK 391      // dst buckets of 256 nodes
#define TILE 4000     // edges per binA tile
#define NBLKA 400     // NE / TILE
#define BCAP 6144     // binB LDS esrc capacity (bucket mean 4092, +32 sigma)
#define NBLKG 782     // gemm blocks: 128 rows each

__device__ __forceinline__ unsigned enc(float f) {
    unsigned u = __float_as_uint(f);
    return (u & 0x80000000u) ? ~u : (u | 0x80000000u);
}
__device__ __forceinline__ float dec(unsigned u) {
    return (u & 0x80000000u) ? __uint_as_float(u & 0x7FFFFFFFu) : __uint_as_float(~u);
}
__device__ __forceinline__ unsigned bfr(float f) {   // fp32 -> bf16 bits, RNE
    unsigned u = __float_as_uint(f);
    return (u + 0x7FFFu + ((u >> 16) & 1)) >> 16;
}
__device__ __forceinline__ float blo(unsigned w) { return __uint_as_float(w << 16); }
__device__ __forceinline__ float bhi(unsigned w) { return __uint_as_float(w & 0xFFFF0000u); }

// fp32 [NN][64] -> bf16-packed [NN][32] u32
__global__ void k_cast(const float4* __restrict__ in, uint2* __restrict__ out, int n4) {
    int i = blockIdx.x * 256 + threadIdx.x;
    if (i < n4) {
        float4 v = in[i];
        out[i] = make_uint2(bfr(v.x) | (bfr(v.y) << 16), bfr(v.z) | (bfr(v.w) << 16));
    }
}

// ---- pass A1: per-(tile,bucket) histogram ----
__launch_bounds__(256)
__global__ void k_binA1(const int* __restrict__ dst, int* __restrict__ cntA) {
    __shared__ int cnt[NBUK];
    int tid = threadIdx.x, blk = blockIdx.x;
    for (int i = tid; i < NBUK; i += 256) cnt[i] = 0;
    __syncthreads();
    int e0 = blk * TILE, e1 = min(e0 + TILE, NE);
    for (int e = e0 + tid; e < e1; e += 256) atomicAdd(&cnt[dst[e] >> 8], 1);
    __syncthreads();
    for (int i = tid; i < NBUK; i += 256) cntA[blk * NBUK + i] = cnt[i];
}

// ---- per-bucket exclusive scan over tiles (exact offsets) ----
__global__ void k_scanA(const int* __restrict__ cntA, int* __restrict__ cofs,
                        int* __restrict__ buktot) {
    __shared__ int s[256];
    int b = blockIdx.x, t = threadIdx.x;
    int v0 = 0, v1 = 0;
    if (t < NBLKA / 2) {
        v0 = cntA[(2 * t) * NBUK + b];
        v1 = cntA[(2 * t + 1) * NBUK + b];
    }
    int sum = v0 + v1;
    s[t] = sum;
    __syncthreads();
    for (int off = 1; off < 256; off <<= 1) {
        int y = (t >= off) ? s[t - off] : 0;
        __syncthreads();
        s[t] += y;
        __syncthreads();
    }
    int excl = s[t] - sum;
    if (t < NBLKA / 2) {
        cofs[(2 * t) * NBUK + b] = excl;
        cofs[(2 * t + 1) * NBUK + b] = excl + v0;
    }
    if (t == 255) buktot[b] = s[255];
}

// ---- exclusive scan of 391 bucket totals ----
__global__ void k_bukscan(const int* __restrict__ buktot, int* __restrict__ bukbase) {
    __shared__ int s[512];
    int t = threadIdx.x;
    int c = (t < NBUK) ? buktot[t] : 0;
    s[t] = c;
    __syncthreads();
    for (int off = 1; off < 512; off <<= 1) {
        int y = (t >= off) ? s[t - off] : 0;
        __syncthreads();
        s[t] += y;
        __syncthreads();
    }
    if (t < NBUK) bukbase[t] = s[t] - c;
}

// ---- pass A2: coalesced src/ea reads, exact-position scattered writes ----
__launch_bounds__(256)
__global__ void k_binA2(const int* __restrict__ dst, const int* __restrict__ src,
                        const float* __restrict__ ea, const int* __restrict__ bukbase,
                        const int* __restrict__ cofs,
                        unsigned* __restrict__ w0, float* __restrict__ ea6) {
    __shared__ int cursor[NBUK];
    int tid = threadIdx.x, blk = blockIdx.x;
    for (int i = tid; i < NBUK; i += 256) cursor[i] = bukbase[i] + cofs[blk * NBUK + i];
    __syncthreads();
    int e0 = blk * TILE, e1 = min(e0 + TILE, NE);
    for (int e = e0 + tid; e < e1; e += 256) {
        int d = dst[e], s = src[e];
        int b = d >> 8;
        int pos = atomicAdd(&cursor[b], 1);
        w0[pos] = ((unsigned)s << 8) | (unsigned)(d & 255);
        const float* pe = &ea[(size_t)e * DE];
        float* po = &ea6[(size_t)pos * DE];
        #pragma unroll
        for (int t = 0; t < DE; ++t) po[t] = pe[t];
    }
}

// ---- pass B: stream bucket region; rowptr + esrc scatter + eagg (all LDS) ----
__launch_bounds__(256)
__global__ void k_binB(const unsigned* __restrict__ w0, const float* __restrict__ ea6,
                       const int* __restrict__ bukbase, const int* __restrict__ buktot,
                       int* __restrict__ rowptr, int* __restrict__ esrc,
                       unsigned* __restrict__ eaggk) {
    __shared__ int cnt[256];
    __shared__ int base[256];
    __shared__ unsigned el[BCAP];            // 24 KB
    __shared__ unsigned emax[256 * DE];      // 6 KB
    int b = blockIdx.x, tid = threadIdx.x;
    int nb = b << 8;
    int nend = min(nb + 256, NN);
    int rb = bukbase[b];
    int tot = buktot[b];
    cnt[tid] = 0;
    for (int i = tid; i < 256 * DE; i += 256) emax[i] = ENC_NEGINF;
    __syncthreads();
    // counts
    for (int i = tid; i < tot; i += 256) atomicAdd(&cnt[w0[rb + i] & 255], 1);
    __syncthreads();
    int v = cnt[tid];
    base[tid] = v;
    __syncthreads();
    for (int off = 1; off < 256; off <<= 1) {
        int y = (tid >= off) ? base[tid - off] : 0;
        __syncthreads();
        base[tid] += y;
        __syncthreads();
    }
    int excl = base[tid] - v;
    if (nb + tid < NN) rowptr[nb + tid] = rb + excl;
    if (b == NBUK - 1 && tid == 0) rowptr[NN] = NE;
    __syncthreads();
    cnt[tid] = excl;   // cursor (global positions within bucket)
    __syncthreads();
    if (tot <= BCAP) {
        for (int i = tid; i < tot; i += 256) {
            unsigned ww = w0[rb + i];
            int loc = ww & 255;
            int pos = atomicAdd(&cnt[loc], 1);
            el[pos] = ww >> 8;
            const float* pe = &ea6[(size_t)(rb + i) * DE];
            #pragma unroll
            for (int t = 0; t < DE; ++t) atomicMax(&emax[loc * DE + t], enc(pe[t]));
        }
        __syncthreads();
        for (int i = tid; i < tot; i += 256) esrc[rb + i] = (int)el[i];
    } else {  // freak-overflow fallback: 4 loc-quarters, each staged separately
        for (int h = 0; h < 4; ++h) {
            int lo = h * 64;
            int beg = (h == 0) ? 0 : base[lo - 1];
            int sz = base[lo + 63] - beg;
            for (int i = tid; i < tot; i += 256) {
                unsigned ww = w0[rb + i];
                int loc = ww & 255;
                if ((loc >> 6) == h) {
                    int pos = atomicAdd(&cnt[loc], 1);
                    el[pos - beg] = ww >> 8;
                    const float* pe = &ea6[(size_t)(rb + i) * DE];
                    #pragma unroll
                    for (int t = 0; t < DE; ++t) atomicMax(&emax[loc * DE + t], enc(pe[t]));
                }
            }
            __syncthreads();
            for (int i = tid; i < sz; i += 256) esrc[rb + beg + i] = (int)el[i];
            __syncthreads();
        }
    }
    __syncthreads();
    for (int i = tid; i < (nend - nb) * DE; i += 256) eaggk[nb * DE + i] = emax[i];
}

// ---------------- gather-max: half-wave per node, raw bf16 maxima out ----------------
__global__ void k_agg(const unsigned* __restrict__ Xb, const int* __restrict__ rowptr,
                      const int* __restrict__ esrc, unsigned* __restrict__ Ab) {
    int n = blockIdx.x * 8 + (threadIdx.x >> 5);
    int lt = threadIdx.x & 31;
    if (n >= NN) return;
    int rs = rowptr[n], re = rowptr[n + 1];
    float m0 = NINF, m1 = NINF, p0 = NINF, p1 = NINF;
    int j = rs;
    for (; j + 16 <= re; j += 16) {
        unsigned v0 = Xb[(size_t)esrc[j + 0] * 32 + lt],  v1 = Xb[(size_t)esrc[j + 1] * 32 + lt];
        unsigned v2 = Xb[(size_t)esrc[j + 2] * 32 + lt],  v3 = Xb[(size_t)esrc[j + 3] * 32 + lt];
        unsigned v4 = Xb[(size_t)esrc[j + 4] * 32 + lt],  v5 = Xb[(size_t)esrc[j + 5] * 32 + lt];
        unsigned v6 = Xb[(size_t)esrc[j + 6] * 32 + lt],  v7 = Xb[(size_t)esrc[j + 7] * 32 + lt];
        unsigned v8 = Xb[(size_t)esrc[j + 8] * 32 + lt],  v9 = Xb[(size_t)esrc[j + 9] * 32 + lt];
        unsigned va = Xb[(size_t)esrc[j + 10] * 32 + lt], vb = Xb[(size_t)esrc[j + 11] * 32 + lt];
        unsigned vc = Xb[(size_t)esrc[j + 12] * 32 + lt], vd = Xb[(size_t)esrc[j + 13] * 32 + lt];
        unsigned ve = Xb[(size_t)esrc[j + 14] * 32 + lt], vf = Xb[(size_t)esrc[j + 15] * 32 + lt];
        m0 = fmaxf(m0, fmaxf(fmaxf(blo(v0), blo(v1)), fmaxf(blo(v2), blo(v3))));
        p0 = fmaxf(p0, fmaxf(fmaxf(blo(v4), blo(v5)), fmaxf(blo(v6), blo(v7))));
        m0 = fmaxf(m0, fmaxf(fmaxf(blo(v8), blo(v9)), fmaxf(blo(va), blo(vb))));
        p0 = fmaxf(p0, fmaxf(fmaxf(blo(vc), blo(vd)), fmaxf(blo(ve), blo(vf))));
        m1 = fmaxf(m1, fmaxf(fmaxf(bhi(v0), bhi(v1)), fmaxf(bhi(v2), bhi(v3))));
        p1 = fmaxf(p1, fmaxf(fmaxf(bhi(v4), bhi(v5)), fmaxf(bhi(v6), bhi(v7))));
        m1 = fmaxf(m1, fmaxf(fmaxf(bhi(v8), bhi(v9)), fmaxf(bhi(va), bhi(vb))));
        p1 = fmaxf(p1, fmaxf(fmaxf(bhi(vc), bhi(vd)), fmaxf(bhi(ve), bhi(vf))));
    }
    for (; j + 4 <= re; j += 4) {
        unsigned v0 = Xb[(size_t)esrc[j + 0] * 32 + lt], v1 = Xb[(size_t)esrc[j + 1] * 32 + lt];
        unsigned v2 = Xb[(size_t)esrc[j + 2] * 32 + lt], v3 = Xb[(size_t)esrc[j + 3] * 32 + lt];
        m0 = fmaxf(m0, fmaxf(blo(v0), blo(v1))); p0 = fmaxf(p0, fmaxf(blo(v2), blo(v3)));
        m1 = fmaxf(m1, fmaxf(bhi(v0), bhi(v1))); p1 = fmaxf(p1, fmaxf(bhi(v2), bhi(v3)));
    }
    for (; j < re; ++j) {
        unsigned v = Xb[(size_t)esrc[j] * 32 + lt];
        m0 = fmaxf(m0, blo(v)); m1 = fmaxf(m1, bhi(v));
    }
    m0 = fmaxf(m0, p0);
    m1 = fmaxf(m1, p1);
    Ab[(size_t)n * 32 + lt] = bfr(m0) | (bfr(m1) << 16);
}

// ---------------- GEMM: 128 rows/block, per-block stats stores ----------------
__launch_bounds__(512)
__global__ void k_gemm(const unsigned* __restrict__ Ab, const unsigned* __restrict__ eaggk,
                       const float* __restrict__ ss, int apply,
                       const float* __restrict__ W, const float* __restrict__ b,
                       unsigned* __restrict__ Hb, float* __restrict__ pstats) {
    __shared__ float Wl[72][68];     // 19.1 KB
    __shared__ float Ag[128][76];    // 38.9 KB
    __shared__ float ls[128];

    int tid = threadIdx.x;
    int n0 = blockIdx.x * 128;

    const float4* W4 = (const float4*)W;
    for (int i = tid; i < 72 * 16; i += 512) {
        int k = i >> 4, j4 = i & 15;
        float4 v = (k < FAN) ? W4[i] : make_float4(0.f, 0.f, 0.f, 0.f);
        *(float4*)&Wl[k][j4 * 4] = v;
    }
    const uint2* Ab2 = (const uint2*)Ab;
    for (int i = tid; i < 128 * 16; i += 512) {
        int r = i >> 4, c4 = i & 15;
        int n = n0 + r;
        uint2 wv = (n < NN) ? Ab2[(size_t)n * 16 + c4] : make_uint2(0xFF80FF80u, 0xFF80FF80u);
        float a0 = blo(wv.x), a1 = bhi(wv.x), a2 = blo(wv.y), a3 = bhi(wv.y);
        if (apply) {
            int c = 4 * c4;
            a0 = (a0 == NINF) ? 0.f : fmaxf(fmaf(a0, ss[c + 0], ss[D + c + 0]), 0.f);
            a1 = (a1 == NINF) ? 0.f : fmaxf(fmaf(a1, ss[c + 1], ss[D + c + 1]), 0.f);
            a2 = (a2 == NINF) ? 0.f : fmaxf(fmaf(a2, ss[c + 2], ss[D + c + 2]), 0.f);
            a3 = (a3 == NINF) ? 0.f : fmaxf(fmaf(a3, ss[c + 3], ss[D + c + 3]), 0.f);
        } else {
            a0 = (a0 == NINF) ? 0.f : a0;
            a1 = (a1 == NINF) ? 0.f : a1;
            a2 = (a2 == NINF) ? 0.f : a2;
            a3 = (a3 == NINF) ? 0.f : a3;
        }
        *(float4*)&Ag[r][4 * c4] = make_float4(a0, a1, a2, a3);
    }
    for (int i = tid; i < 128 * 8; i += 512) {
        int r = i >> 3, c = i & 7;
        int n = n0 + r;
        float v = 0.f;
        if (c < DE && n < NN) {
            unsigned u = eaggk[n * DE + c];
            v = (u == ENC_NEGINF) ? 0.f : dec(u);
        }
        Ag[r][64 + c] = v;
    }
    if (tid < 128) ls[tid] = 0.f;
    __syncthreads();

    int tr = tid >> 4, tc = tid & 15;
    int c0 = tc * 4;
    float acc[4][4];
    #pragma unroll
    for (int i = 0; i < 4; i++)
        #pragma unroll
        for (int jj = 0; jj < 4; jj++) acc[i][jj] = 0.f;

    for (int kb = 0; kb < 18; ++kb) {
        int k4 = kb * 4;
        float a[4][4], wr[4][4];
        *(float4*)&a[0][0] = *(const float4*)&Ag[tr +  0][k4];
        *(float4*)&a[1][0] = *(const float4*)&Ag[tr + 32][k4];
        *(float4*)&a[2][0] = *(const float4*)&Ag[tr + 64][k4];
        *(float4*)&a[3][0] = *(const float4*)&Ag[tr + 96][k4];
        *(float4*)&wr[0][0] = *(const float4*)&Wl[k4 + 0][c0];
        *(float4*)&wr[1][0] = *(const float4*)&Wl[k4 + 1][c0];
        *(float4*)&wr[2][0] = *(const float4*)&Wl[k4 + 2][c0];
        *(float4*)&wr[3][0] = *(const float4*)&Wl[k4 + 3][c0];
        #pragma unroll
        for (int kk = 0; kk < 4; ++kk)
            #pragma unroll
            for (int i = 0; i < 4; ++i)
                #pragma unroll
                for (int jj = 0; jj < 4; ++jj)
                    acc[i][jj] = fmaf(a[i][kk], wr[kk][jj], acc[i][jj]);
    }

    float4 bb = *(const float4*)&b[c0];
    float cs[4] = {0.f, 0.f, 0.f, 0.f};
    float cq[4] = {0.f, 0.f, 0.f, 0.f};
    #pragma unroll
    for (int i = 0; i < 4; i++) {
        int n = n0 + tr + 32 * i;
        if (n < NN) {
            float ox = acc[i][0] + bb.x, oy = acc[i][1] + bb.y;
            float oz = acc[i][2] + bb.z, ow = acc[i][3] + bb.w;
            uint2 pk = make_uint2(bfr(ox) | (bfr(oy) << 16), bfr(oz) | (bfr(ow) << 16));
            *(uint2*)&Hb[(size_t)n * 32 + 2 * tc] = pk;
            cs[0] += ox; cs[1] += oy; cs[2] += oz; cs[3] += ow;
            cq[0] += ox * ox; cq[1] += oy * oy; cq[2] += oz * oz; cq[3] += ow * ow;
        }
    }
    #pragma unroll
    for (int jj = 0; jj < 4; jj++) {
        atomicAdd(&ls[c0 + jj], cs[jj]);          // LDS only
        atomicAdd(&ls[64 + c0 + jj], cq[jj]);
    }
    __syncthreads();
    if (tid < 128) pstats[(size_t)blockIdx.x * 128 + tid] = ls[tid];
}

// reduce per-block stats + finalize scale/shift
__global__ void k_redfin(const float* __restrict__ pstats, const float* __restrict__ g,
                         const float* __restrict__ beta, float* __restrict__ ss) {
    __shared__ float red[8][128];
    __shared__ float tot[128];
    int tid = threadIdx.x;
    int j = tid & 127, seg = tid >> 7;
    float s = 0.f;
    for (int blk = seg; blk < NBLKG; blk += 8) s += pstats[(size_t)blk * 128 + j];
    red[seg][j] = s;
    __syncthreads();
    if (tid < 128) {
        float t = 0.f;
        #pragma unroll
        for (int k = 0; k < 8; ++k) t += red[k][tid];
        tot[tid] = t;
    }
    __syncthreads();
    if (tid < 64) {
        float mean = tot[tid] * (1.0f / NN);
        float var = tot[64 + tid] * (1.0f / NN) - mean * mean;
        float sc = rsqrtf(var + EPS) * g[tid];
        ss[tid] = sc;
        ss[64 + tid] = beta[tid] - mean * sc;
    }
}

// graph offsets from sorted batch
__global__ void k_gptr(const int* __restrict__ batch, int* __restrict__ gptr) {
    int i = blockIdx.x * 256 + threadIdx.x;
    if (i >= NN) return;
    int b = batch[i];
    int prev = (i == 0) ? -1 : batch[i - 1];
    for (int g = prev + 1; g <= b; ++g) gptr[g] = i;
    if (i == NN - 1) {
        for (int g = b + 1; g <= NG; ++g) gptr[g] = NN;
    }
}

// pool(gather) + norm/relu + dot: half-wave per graph
__global__ void k_gfinal(const unsigned* __restrict__ Hb, const int* __restrict__ gptr,
                         const float* __restrict__ ss, const float* __restrict__ lw,
                         const float* __restrict__ lb, float* __restrict__ out) {
    int g = blockIdx.x * 8 + (threadIdx.x >> 5);
    int lt = threadIdx.x & 31;
    if (g >= NG) return;
    int rs = gptr[g], re = gptr[g + 1];
    float m0 = NINF, m1 = NINF, p0 = NINF, p1 = NINF;
    int n = rs;
    for (; n + 4 <= re; n += 4) {
        unsigned v0 = Hb[(size_t)(n + 0) * 32 + lt];
        unsigned v1 = Hb[(size_t)(n + 1) * 32 + lt];
        unsigned v2 = Hb[(size_t)(n + 2) * 32 + lt];
        unsigned v3 = Hb[(size_t)(n + 3) * 32 + lt];
        m0 = fmaxf(m0, fmaxf(blo(v0), blo(v1))); m1 = fmaxf(m1, fmaxf(bhi(v0), bhi(v1)));
        p0 = fmaxf(p0, fmaxf(blo(v2), blo(v3))); p1 = fmaxf(p1, fmaxf(bhi(v2), bhi(v3)));
    }
    for (; n < re; ++n) {
        unsigned v = Hb[(size_t)n * 32 + lt];
        m0 = fmaxf(m0, blo(v)); m1 = fmaxf(m1, bhi(v));
    }
    m0 = fmaxf(m0, p0);
    m1 = fmaxf(m1, p1);
    float a0 = (m0 == NINF) ? 0.f : fmaxf(fmaf(m0, ss[2 * lt], ss[D + 2 * lt]), 0.f);
    float a1 = (m1 == NINF) ? 0.f : fmaxf(fmaf(m1, ss[2 * lt + 1], ss[D + 2 * lt + 1]), 0.f);
    float p = fmaf(a0, lw[2 * lt], a1 * lw[2 * lt + 1]);
    #pragma unroll
    for (int off = 1; off < 32; off <<= 1) p += __shfl_xor(p, off);
    if (lt == 0) out[g] = p + lb[0];
}

extern "C" void kernel_launch(void* const* d_in, const int* in_sizes, int n_in,
                              void* d_out, int out_size, void* d_ws, size_t ws_size,
                              hipStream_t stream) {
    const float* x     = (const float*)d_in[0];
    const int*   ei    = (const int*)d_in[1];
    const float* ea    = (const float*)d_in[2];
    const int*   batch = (const int*)d_in[3];
    const float* Wp[3] = {(const float*)d_in[4],  (const float*)d_in[8],  (const float*)d_in[12]};
    const float* bp[3] = {(const float*)d_in[5],  (const float*)d_in[9],  (const float*)d_in[13]};
    const float* gp[3] = {(const float*)d_in[6],  (const float*)d_in[10], (const float*)d_in[14]};
    const float* tp[3] = {(const float*)d_in[7],  (const float*)d_in[11], (const float*)d_in[15]};
    const float* lw    = (const float*)d_in[16];
    const float* lb    = (const float*)d_in[17];
    float* out = (float*)d_out;

    const int* src = ei;
    const int* dst = ei + NE;

    // workspace layout (u32 word offsets); total 55.26 MB
    unsigned* w = (unsigned*)d_ws;
    int*      rowptr  = (int*)w;                   // 100004
    int*      esrc    = (int*)(w + 100004);        // 1600000
    unsigned* eaggk   = w + 1700004;               // 600000
    float*    ss      = (float*)(w + 2300004);     // 128
    int*      gptr    = (int*)(w + 2300132);       // 1032
    int*      buktot  = (int*)(w + 2301164);       // 400
    int*      bukbase = (int*)(w + 2301564);       // 400
    int*      cntA    = (int*)(w + 2301964);       // NBLKA*NBUK = 156400
    int*      cofs    = (int*)(w + 2458364);       // 156400 -> end 2614764
    float*    pstats  = (float*)(w + 2301964);     // 100096 (alias cntA; disjoint lifetime)
    unsigned* w0      = w + 2614764;               // 1600000 -> end 4214764
    unsigned* POOL    = w + 4214764;               // ea6: 9600000 -> end 13814764 (55.26 MB)
    float*    ea6     = (float*)POOL;
    unsigned* P       = POOL;                      // 3200000 (alias ea6; post-binB)
    unsigned* Q       = POOL + 3200000;            // 3200000

    // --- CSR + eagg: exact-placement binning (no global atomics, no fills) ---
    k_binA1<<<NBLKA, 256, 0, stream>>>(dst, cntA);
    k_scanA<<<NBUK, 256, 0, stream>>>(cntA, cofs, buktot);
    k_bukscan<<<1, 512, 0, stream>>>(buktot, bukbase);
    k_binA2<<<NBLKA, 256, 0, stream>>>(dst, src, ea, bukbase, cofs, w0, ea6);
    k_binB<<<NBUK, 256, 0, stream>>>(w0, ea6, bukbase, buktot, rowptr, esrc, eaggk);

    // --- bf16 cast (AFTER binB: P aliases ea6) + graph offsets ---
    k_cast<<<(NN * 16 + 255) / 256, 256, 0, stream>>>((const float4*)x, (uint2*)P, NN * 16);
    k_gptr<<<(NN + 255) / 256, 256, 0, stream>>>(batch, gptr);

    // --- 3 layers: 2-buffer ping-pong (agg P->Q, gemm Q->P) ---
    for (int l = 0; l < 3; ++l) {
        k_agg<<<NN / 8, 256, 0, stream>>>(P, rowptr, esrc, Q);
        k_gemm<<<NBLKG, 512, 0, stream>>>(Q, eaggk, ss, l > 0 ? 1 : 0,
                                          Wp[l], bp[l], P, pstats);
        k_redfin<<<1, 1024, 0, stream>>>(pstats, gp[l], tp[l], ss);
    }

    // --- pooled gather + final norm/relu/dot ---
    k_gfinal<<<NG / 8, 256, 0, stream>>>(P, gptr, ss, lw, lb, out);
}